// Round 8
// baseline (859.368 us; speedup 1.0000x reference)
//
#include <hip/hip_runtime.h>
#include <hip/hip_bf16.h>

#define F 64
#define RB 256            // nodes per bucket (power of 2)
#define RBSH 8
#define NBMAX 400         // N=100000 -> NB=391
#define CHUNKA 8192       // edges per passA block

typedef int   nt_int4   __attribute__((ext_vector_type(4)));
typedef float nt_float4 __attribute__((ext_vector_type(4)));

__device__ __forceinline__ unsigned short f2bf(float f) {
    unsigned int u = __float_as_uint(f);
    unsigned int r = (u + 0x7FFFu + ((u >> 16) & 1u)) >> 16;   // RNE
    return (unsigned short)r;
}
__device__ __forceinline__ float bf2f(unsigned short h) {
    return __uint_as_float(((unsigned int)h) << 16);
}

// ---------------------------------------------------------------------------
// Stage 1: EvolveGCN-O GRU on the [64,64] weight -> W_new transposed.
// ---------------------------------------------------------------------------
__global__ void evolve_kernel(const float* __restrict__ W,
                              const float* __restrict__ wih,
                              const float* __restrict__ whh,
                              const float* __restrict__ bih,
                              const float* __restrict__ bhh,
                              float* __restrict__ wt) {
    int t = blockIdx.x * blockDim.x + threadIdx.x;
    if (t >= F * F) return;
    int i = t >> 6;
    int j = t & 63;
    const float* Wi = W + i * F;
    float gxr = bih[j], gxz = bih[F + j], gxn = bih[2 * F + j];
    float ghr = bhh[j], ghz = bhh[F + j], ghn = bhh[2 * F + j];
#pragma unroll
    for (int k = 0; k < F; ++k) {
        float wv = Wi[k];
        gxr += wv * wih[(j) * F + k];
        gxz += wv * wih[(F + j) * F + k];
        gxn += wv * wih[(2 * F + j) * F + k];
        ghr += wv * whh[(j) * F + k];
        ghz += wv * whh[(F + j) * F + k];
        ghn += wv * whh[(2 * F + j) * F + k];
    }
    float r = 1.0f / (1.0f + expf(-(gxr + ghr)));
    float z = 1.0f / (1.0f + expf(-(gxz + ghz)));
    float n = tanhf(gxn + r * ghn);
    float wnew = (1.0f - z) * n + z * Wi[j];
    wt[j * F + i] = wnew;                      // transposed: wt[col][k]
}

// ---------------------------------------------------------------------------
// Stage 2: xw16 = bf16( rsqrt(deg[r]) * (x @ W_new) ). dinv[src] folded in.
// ---------------------------------------------------------------------------
__global__ void xw_kernel(const float* __restrict__ x,
                          const float* __restrict__ wt,
                          const float* __restrict__ deg,
                          unsigned short* __restrict__ xw16, int N) {
    int r = blockIdx.x * blockDim.x + threadIdx.x;
    if (r >= N) return;
    float xr[F];
    const nt_float4* xp = (const nt_float4*)(x + (size_t)r * F);
#pragma unroll
    for (int q = 0; q < F / 4; ++q) {
        nt_float4 v = __builtin_nontemporal_load(xp + q);
        xr[4 * q + 0] = v.x; xr[4 * q + 1] = v.y;
        xr[4 * q + 2] = v.z; xr[4 * q + 3] = v.w;
    }
    float dinv = rsqrtf(deg[r]);
    ushort4* op = (ushort4*)(xw16 + (size_t)r * F);
    for (int cb = 0; cb < F / 4; ++cb) {
        const float* w0 = wt + (4 * cb) * F;
        float a0 = 0.f, a1 = 0.f, a2 = 0.f, a3 = 0.f;
#pragma unroll
        for (int k = 0; k < F; ++k) {
            float xv = xr[k];
            a0 += xv * w0[k];
            a1 += xv * w0[F + k];
            a2 += xv * w0[2 * F + k];
            a3 += xv * w0[3 * F + k];
        }
        ushort4 o;
        o.x = f2bf(a0 * dinv); o.y = f2bf(a1 * dinv);
        o.z = f2bf(a2 * dinv); o.w = f2bf(a3 * dinv);
        op[cb] = o;
    }
}

// ---------------------------------------------------------------------------
// Stage 3a: bucket histogram (bucket = dst>>8). LDS hist per block, one
// global atomic per (block,bucket) at merge.
// ---------------------------------------------------------------------------
__global__ void bhist_kernel(const int* __restrict__ ei, int* __restrict__ ghist,
                             int E, int NB) {
    __shared__ int lh[NBMAX];
    int t = threadIdx.x;
    for (int i = t; i < NB; i += 256) lh[i] = 0;
    __syncthreads();
    int base = blockIdx.x * 4096;
#pragma unroll
    for (int it = 0; it < 16; ++it) {
        int e = base + it * 256 + t;
        if (e < E) atomicAdd(&lh[ei[E + e] >> RBSH], 1);
    }
    __syncthreads();
    for (int i = t; i < NB; i += 256) {
        int c = lh[i];
        if (c) atomicAdd(&ghist[i], c);
    }
}

// ---------------------------------------------------------------------------
// Stage 3b: exclusive scan of NB bucket counts (single block).
// ---------------------------------------------------------------------------
__global__ void bscan_kernel(const int* __restrict__ ghist, int* __restrict__ boff,
                             int* __restrict__ gcur, int NB) {
    __shared__ int s[512];
    int t = threadIdx.x;
    int v = (t < NB) ? ghist[t] : 0;
    s[t] = v;
    __syncthreads();
    for (int o = 1; o < 512; o <<= 1) {
        int u = (t >= o) ? s[t - o] : 0;
        __syncthreads();
        s[t] += u;
        __syncthreads();
    }
    if (t < NB) {
        int excl = s[t] - v;
        boff[t] = excl;
        gcur[t] = excl;
        if (t == NB - 1) boff[NB] = excl + v;   // == E
    }
}

// ---------------------------------------------------------------------------
// Stage 3c (passA): bucketed scatter with per-(block,bucket) contiguous runs.
// Phase 1: LDS bucket hist over the block's 8192-edge chunk (warms L2).
// Phase 2: ONE global atomicAdd per non-empty bucket reserves a run.
// Phase 3: re-read chunk (L2-hot), write 8B records via LDS cursors.
// All stores of a run issue from one CU back-to-back -> lines fill in the
// local L2 and write back ONCE (kills the ~64B/store write-through).
// Record: [dstlocal:8 | src:17 | w:15] in low 40 bits of u64.
// ---------------------------------------------------------------------------
__global__ void passA_kernel(const int* __restrict__ ei, const float* __restrict__ ew,
                             int* __restrict__ gcur,
                             unsigned long long* __restrict__ rec, int E, int NB) {
    __shared__ int lh[NBMAX];
    __shared__ int lcur[NBMAX];
    int t = threadIdx.x;
    for (int i = t; i < NB; i += 256) lh[i] = 0;
    __syncthreads();
    int base = blockIdx.x * CHUNKA;
#pragma unroll
    for (int it = 0; it < CHUNKA / 256; ++it) {
        int e = base + it * 256 + t;
        if (e < E) atomicAdd(&lh[ei[E + e] >> RBSH], 1);
    }
    __syncthreads();
    for (int i = t; i < NB; i += 256) {
        int c = lh[i];
        lcur[i] = c ? atomicAdd(&gcur[i], c) : 0;
    }
    __syncthreads();
#pragma unroll
    for (int it = 0; it < CHUNKA / 256; ++it) {
        int e = base + it * 256 + t;
        if (e < E) {
            int dst = ei[E + e];
            int src = ei[e];
            float w = ew[e];
            unsigned int q = (unsigned int)(w * 32767.0f + 0.5f);
            int b = dst >> RBSH;
            int p = atomicAdd(&lcur[b], 1);
            unsigned long long r = ((unsigned long long)(dst & (RB - 1)) << 32)
                                 | ((unsigned long long)((unsigned int)src) << 15) | q;
            rec[p] = r;
        }
    }
}

// ---------------------------------------------------------------------------
// Stage 4 (passB): block per bucket. 64KB LDS fp32 accumulator [RB][F].
// 8 waves stream the bucket's records: broadcast 8B record, gather 128B
// xw16 row (lane=feature), ds_add_f32 into acc. Epilogue: ReLU * lw,
// shuffle-reduce, * rsqrt(deg[dst]), + lb -> out. No per-node sort needed.
// ---------------------------------------------------------------------------
__global__ void __launch_bounds__(512) passB_kernel(
        const unsigned short* __restrict__ xw16,
        const int* __restrict__ boff,
        const unsigned long long* __restrict__ rec,
        const float* __restrict__ deg,
        const float* __restrict__ lw,
        const float* __restrict__ lb,
        float* __restrict__ out, int N, int M) {
    __shared__ float acc[RB * F];     // 64KB
    int t = threadIdx.x;
    int b = blockIdx.x;
    for (int i = t; i < RB * F; i += 512) acc[i] = 0.0f;
    __syncthreads();
    int beg = boff[b];
    int end = boff[b + 1];
    int lane = t & 63;
    int wv = t >> 6;                  // 8 waves
    const float wscale = 1.0f / 32767.0f;
    for (int i = beg + wv * 4; i < end; i += 32) {
#pragma unroll
        for (int k = 0; k < 4; ++k) {
            int j = i + k;
            if (j < end) {
                unsigned long long r = rec[j];
                float w = (float)((unsigned int)r & 32767u) * wscale;
                int src = (int)((r >> 15) & 0x1FFFFu);
                int dl = (int)(r >> 32);
                float v = bf2f(xw16[(size_t)src * F + lane]);
                atomicAdd(&acc[dl * F + lane], w * v);
            }
        }
    }
    __syncthreads();
    int node0 = b << RBSH;
    for (int nl = wv; nl < RB; nl += 8) {
        int node = node0 + nl;
        if (node < N && node < M) {
            float a = acc[nl * F + lane];
            a = fmaxf(a, 0.0f) * lw[lane];
#pragma unroll
            for (int o = 32; o; o >>= 1) a += __shfl_xor(a, o, 64);
            if (lane == 0) out[node] = a * rsqrtf(deg[node]) + lb[0];
        }
    }
}

extern "C" void kernel_launch(void* const* d_in, const int* in_sizes, int n_in,
                              void* d_out, int out_size, void* d_ws, size_t ws_size,
                              hipStream_t stream) {
    const float* x   = (const float*)d_in[0];
    const int*   ei  = (const int*)d_in[1];
    const float* ew  = (const float*)d_in[2];
    const float* deg = (const float*)d_in[3];
    const float* W0  = (const float*)d_in[5];
    const float* wih = (const float*)d_in[6];
    const float* whh = (const float*)d_in[7];
    const float* bih = (const float*)d_in[8];
    const float* bhh = (const float*)d_in[9];
    const float* lw  = (const float*)d_in[10];
    const float* lb  = (const float*)d_in[11];
    float* out = (float*)d_out;

    int N = in_sizes[0] / F;        // 100000
    int E = in_sizes[1] / 2;        // 1600000
    int M = out_size;               // target_num
    int NB = (N + RB - 1) / RB;     // 391 (must be <= NBMAX)

    // workspace layout (8B alignment maintained for rec)
    float*              wt    = (float*)d_ws;                       // 8192 f (32KB)
    unsigned short*     xw16  = (unsigned short*)(wt + 8192);       // N*F bf16 (12.8MB)
    unsigned long long* rec   = (unsigned long long*)(xw16 + (size_t)N * F);  // E u64 (12.8MB)
    int*                ghist = (int*)(rec + E);                    // NB
    int*                boff  = ghist + NBMAX;                      // NB+1
    int*                gcur  = boff + NBMAX + 8;                   // NB

    evolve_kernel<<<(F * F + 255) / 256, 256, 0, stream>>>(W0, wih, whh, bih, bhh, wt);

    (void)hipMemsetAsync(ghist, 0, (size_t)NBMAX * sizeof(int), stream);

    xw_kernel<<<(N + 255) / 256, 256, 0, stream>>>(x, wt, deg, xw16, N);

    bhist_kernel<<<(E + 4095) / 4096, 256, 0, stream>>>(ei, ghist, E, NB);

    bscan_kernel<<<1, 512, 0, stream>>>(ghist, boff, gcur, NB);

    passA_kernel<<<(E + CHUNKA - 1) / CHUNKA, 256, 0, stream>>>(ei, ew, gcur, rec, E, NB);

    passB_kernel<<<NB, 512, 0, stream>>>(xw16, boff, rec, deg, lw, lb, out, N, M);
}

// Round 9
// 841.240 us; speedup vs baseline: 1.0215x; 1.0215x over previous
//
#include <hip/hip_runtime.h>
#include <hip/hip_bf16.h>

#define F 64
#define RB 128            // nodes per bucket (power of 2)
#define RBSH 7
#define NBMAX 800         // N=100000 -> NB=782
#define CHUNKA 8192       // edges per passA block

typedef int   nt_int4   __attribute__((ext_vector_type(4)));
typedef float nt_float4 __attribute__((ext_vector_type(4)));

__device__ __forceinline__ unsigned short f2bf(float f) {
    unsigned int u = __float_as_uint(f);
    unsigned int r = (u + 0x7FFFu + ((u >> 16) & 1u)) >> 16;   // RNE
    return (unsigned short)r;
}
__device__ __forceinline__ float bf2f(unsigned short h) {
    return __uint_as_float(((unsigned int)h) << 16);
}

// ---------------------------------------------------------------------------
// Stage 1: EvolveGCN-O GRU on the [64,64] weight -> W_new transposed.
// ---------------------------------------------------------------------------
__global__ void evolve_kernel(const float* __restrict__ W,
                              const float* __restrict__ wih,
                              const float* __restrict__ whh,
                              const float* __restrict__ bih,
                              const float* __restrict__ bhh,
                              float* __restrict__ wt) {
    int t = blockIdx.x * blockDim.x + threadIdx.x;
    if (t >= F * F) return;
    int i = t >> 6;
    int j = t & 63;
    const float* Wi = W + i * F;
    float gxr = bih[j], gxz = bih[F + j], gxn = bih[2 * F + j];
    float ghr = bhh[j], ghz = bhh[F + j], ghn = bhh[2 * F + j];
#pragma unroll
    for (int k = 0; k < F; ++k) {
        float wv = Wi[k];
        gxr += wv * wih[(j) * F + k];
        gxz += wv * wih[(F + j) * F + k];
        gxn += wv * wih[(2 * F + j) * F + k];
        ghr += wv * whh[(j) * F + k];
        ghz += wv * whh[(F + j) * F + k];
        ghn += wv * whh[(2 * F + j) * F + k];
    }
    float r = 1.0f / (1.0f + expf(-(gxr + ghr)));
    float z = 1.0f / (1.0f + expf(-(gxz + ghz)));
    float n = tanhf(gxn + r * ghn);
    float wnew = (1.0f - z) * n + z * Wi[j];
    wt[j * F + i] = wnew;                      // transposed: wt[col][k]
}

// ---------------------------------------------------------------------------
// Stage 2: xw16 = bf16( rsqrt(deg[r]) * (x @ W_new) ). dinv[src] folded in.
// ---------------------------------------------------------------------------
__global__ void xw_kernel(const float* __restrict__ x,
                          const float* __restrict__ wt,
                          const float* __restrict__ deg,
                          unsigned short* __restrict__ xw16, int N) {
    int r = blockIdx.x * blockDim.x + threadIdx.x;
    if (r >= N) return;
    float xr[F];
    const nt_float4* xp = (const nt_float4*)(x + (size_t)r * F);
#pragma unroll
    for (int q = 0; q < F / 4; ++q) {
        nt_float4 v = __builtin_nontemporal_load(xp + q);
        xr[4 * q + 0] = v.x; xr[4 * q + 1] = v.y;
        xr[4 * q + 2] = v.z; xr[4 * q + 3] = v.w;
    }
    float dinv = rsqrtf(deg[r]);
    ushort4* op = (ushort4*)(xw16 + (size_t)r * F);
    for (int cb = 0; cb < F / 4; ++cb) {
        const float* w0 = wt + (4 * cb) * F;
        float a0 = 0.f, a1 = 0.f, a2 = 0.f, a3 = 0.f;
#pragma unroll
        for (int k = 0; k < F; ++k) {
            float xv = xr[k];
            a0 += xv * w0[k];
            a1 += xv * w0[F + k];
            a2 += xv * w0[2 * F + k];
            a3 += xv * w0[3 * F + k];
        }
        ushort4 o;
        o.x = f2bf(a0 * dinv); o.y = f2bf(a1 * dinv);
        o.z = f2bf(a2 * dinv); o.w = f2bf(a3 * dinv);
        op[cb] = o;
    }
}

// ---------------------------------------------------------------------------
// Stage 3a: bucket histogram (bucket = dst>>RBSH). LDS hist per block, one
// global atomic per (block,bucket) at merge.
// ---------------------------------------------------------------------------
__global__ void bhist_kernel(const int* __restrict__ ei, int* __restrict__ ghist,
                             int E, int NB) {
    __shared__ int lh[NBMAX];
    int t = threadIdx.x;
    for (int i = t; i < NB; i += 256) lh[i] = 0;
    __syncthreads();
    int base = blockIdx.x * 4096;
#pragma unroll
    for (int it = 0; it < 16; ++it) {
        int e = base + it * 256 + t;
        if (e < E) atomicAdd(&lh[ei[E + e] >> RBSH], 1);
    }
    __syncthreads();
    for (int i = t; i < NB; i += 256) {
        int c = lh[i];
        if (c) atomicAdd(&ghist[i], c);
    }
}

// ---------------------------------------------------------------------------
// Stage 3b: exclusive scan of NB (<=1024) bucket counts, single 1024-block.
// ---------------------------------------------------------------------------
__global__ void bscan_kernel(const int* __restrict__ ghist, int* __restrict__ boff,
                             int* __restrict__ gcur, int NB) {
    __shared__ int s[1024];
    int t = threadIdx.x;
    int v = (t < NB) ? ghist[t] : 0;
    s[t] = v;
    __syncthreads();
    for (int o = 1; o < 1024; o <<= 1) {
        int u = (t >= o) ? s[t - o] : 0;
        __syncthreads();
        s[t] += u;
        __syncthreads();
    }
    if (t < NB) {
        int excl = s[t] - v;
        boff[t] = excl;
        gcur[t] = excl;
        if (t == NB - 1) boff[NB] = excl + v;   // == E
    }
}

// ---------------------------------------------------------------------------
// Stage 3c (passA): bucketed scatter with per-(block,bucket) contiguous runs.
// One global atomicAdd per (block,bucket) reserves a run; records of a run
// are written back-to-back from one CU -> lines fill locally, write once.
// Record: [dstlocal:7 | src:17 | w:15] packed in u64.
// ---------------------------------------------------------------------------
__global__ void passA_kernel(const int* __restrict__ ei, const float* __restrict__ ew,
                             int* __restrict__ gcur,
                             unsigned long long* __restrict__ rec, int E, int NB) {
    __shared__ int lh[NBMAX];
    __shared__ int lcur[NBMAX];
    int t = threadIdx.x;
    for (int i = t; i < NB; i += 256) lh[i] = 0;
    __syncthreads();
    int base = blockIdx.x * CHUNKA;
#pragma unroll
    for (int it = 0; it < CHUNKA / 256; ++it) {
        int e = base + it * 256 + t;
        if (e < E) atomicAdd(&lh[ei[E + e] >> RBSH], 1);
    }
    __syncthreads();
    for (int i = t; i < NB; i += 256) {
        int c = lh[i];
        lcur[i] = c ? atomicAdd(&gcur[i], c) : 0;
    }
    __syncthreads();
#pragma unroll
    for (int it = 0; it < CHUNKA / 256; ++it) {
        int e = base + it * 256 + t;
        if (e < E) {
            int dst = ei[E + e];
            int src = ei[e];
            float w = ew[e];
            unsigned int q = (unsigned int)(w * 32767.0f + 0.5f);
            int b = dst >> RBSH;
            int p = atomicAdd(&lcur[b], 1);
            unsigned long long r = ((unsigned long long)(dst & (RB - 1)) << 32)
                                 | ((unsigned long long)((unsigned int)src) << 15) | q;
            rec[p] = r;
        }
    }
}

// ---------------------------------------------------------------------------
// Stage 4 (passB): block per bucket. 32KB LDS fp32 accumulator [RB][F]
// -> 4 blocks/CU x 8 waves = full occupancy (the round-8 failure was 64KB
// LDS + 391 blocks = latency starvation at 27% occupancy).
// Branch-free quad main loop for 4-deep gather ILP.
// ---------------------------------------------------------------------------
__global__ void __launch_bounds__(512) passB_kernel(
        const unsigned short* __restrict__ xw16,
        const int* __restrict__ boff,
        const unsigned long long* __restrict__ rec,
        const float* __restrict__ deg,
        const float* __restrict__ lw,
        const float* __restrict__ lb,
        float* __restrict__ out, int N, int M) {
    __shared__ float acc[RB * F];     // 32KB
    int t = threadIdx.x;
    int b = blockIdx.x;
    for (int i = t; i < RB * F; i += 512) acc[i] = 0.0f;
    __syncthreads();
    int beg = boff[b];
    int end = boff[b + 1];
    int lane = t & 63;
    int wv = t >> 6;                  // 8 waves
    const float wscale = 1.0f / 32767.0f;
    int i = beg + wv * 4;
    for (; i + 3 < end; i += 32) {    // full quads, no inner branch
        unsigned long long r0 = rec[i];
        unsigned long long r1 = rec[i + 1];
        unsigned long long r2 = rec[i + 2];
        unsigned long long r3 = rec[i + 3];
        float v0 = bf2f(xw16[(size_t)((r0 >> 15) & 0x1FFFFu) * F + lane]);
        float v1 = bf2f(xw16[(size_t)((r1 >> 15) & 0x1FFFFu) * F + lane]);
        float v2 = bf2f(xw16[(size_t)((r2 >> 15) & 0x1FFFFu) * F + lane]);
        float v3 = bf2f(xw16[(size_t)((r3 >> 15) & 0x1FFFFu) * F + lane]);
        atomicAdd(&acc[(int)(r0 >> 32) * F + lane],
                  (float)((unsigned int)r0 & 32767u) * wscale * v0);
        atomicAdd(&acc[(int)(r1 >> 32) * F + lane],
                  (float)((unsigned int)r1 & 32767u) * wscale * v1);
        atomicAdd(&acc[(int)(r2 >> 32) * F + lane],
                  (float)((unsigned int)r2 & 32767u) * wscale * v2);
        atomicAdd(&acc[(int)(r3 >> 32) * F + lane],
                  (float)((unsigned int)r3 & 32767u) * wscale * v3);
    }
    for (int j = i; j < end && j < i + 4; ++j) {   // tail (<=3 records)
        unsigned long long r = rec[j];
        float v = bf2f(xw16[(size_t)((r >> 15) & 0x1FFFFu) * F + lane]);
        atomicAdd(&acc[(int)(r >> 32) * F + lane],
                  (float)((unsigned int)r & 32767u) * wscale * v);
    }
    __syncthreads();
    int node0 = b << RBSH;
    for (int nl = wv; nl < RB; nl += 8) {
        int node = node0 + nl;
        if (node < N && node < M) {
            float a = acc[nl * F + lane];
            a = fmaxf(a, 0.0f) * lw[lane];
#pragma unroll
            for (int o = 32; o; o >>= 1) a += __shfl_xor(a, o, 64);
            if (lane == 0) out[node] = a * rsqrtf(deg[node]) + lb[0];
        }
    }
}

extern "C" void kernel_launch(void* const* d_in, const int* in_sizes, int n_in,
                              void* d_out, int out_size, void* d_ws, size_t ws_size,
                              hipStream_t stream) {
    const float* x   = (const float*)d_in[0];
    const int*   ei  = (const int*)d_in[1];
    const float* ew  = (const float*)d_in[2];
    const float* deg = (const float*)d_in[3];
    const float* W0  = (const float*)d_in[5];
    const float* wih = (const float*)d_in[6];
    const float* whh = (const float*)d_in[7];
    const float* bih = (const float*)d_in[8];
    const float* bhh = (const float*)d_in[9];
    const float* lw  = (const float*)d_in[10];
    const float* lb  = (const float*)d_in[11];
    float* out = (float*)d_out;

    int N = in_sizes[0] / F;        // 100000
    int E = in_sizes[1] / 2;        // 1600000
    int M = out_size;               // target_num
    int NB = (N + RB - 1) / RB;     // 782 (must be <= NBMAX and <= 1024)

    // workspace layout (8B alignment maintained for rec)
    float*              wt    = (float*)d_ws;                       // 8192 f (32KB)
    unsigned short*     xw16  = (unsigned short*)(wt + 8192);       // N*F bf16 (12.8MB)
    unsigned long long* rec   = (unsigned long long*)(xw16 + (size_t)N * F);  // E u64 (12.8MB)
    int*                ghist = (int*)(rec + E);                    // NB
    int*                boff  = ghist + NBMAX;                      // NB+1
    int*                gcur  = boff + NBMAX + 8;                   // NB

    evolve_kernel<<<(F * F + 255) / 256, 256, 0, stream>>>(W0, wih, whh, bih, bhh, wt);

    (void)hipMemsetAsync(ghist, 0, (size_t)NBMAX * sizeof(int), stream);

    xw_kernel<<<(N + 255) / 256, 256, 0, stream>>>(x, wt, deg, xw16, N);

    bhist_kernel<<<(E + 4095) / 4096, 256, 0, stream>>>(ei, ghist, E, NB);

    bscan_kernel<<<1, 1024, 0, stream>>>(ghist, boff, gcur, NB);

    passA_kernel<<<(E + CHUNKA - 1) / CHUNKA, 256, 0, stream>>>(ei, ew, gcur, rec, E, NB);

    passB_kernel<<<NB, 512, 0, stream>>>(xw16, boff, rec, deg, lw, lb, out, N, M);
}

// Round 10
// 235.807 us; speedup vs baseline: 3.6444x; 3.5675x over previous
//
#include <hip/hip_runtime.h>
#include <hip/hip_bf16.h>

#define F 64
#define RB 128            // nodes per bucket (power of 2)
#define RBSH 7
#define NBMAX 800         // N=100000 -> NB=782
#define CHUNKA 8192       // edges per passA block

typedef int   nt_int4   __attribute__((ext_vector_type(4)));
typedef float nt_float4 __attribute__((ext_vector_type(4)));

__device__ __forceinline__ unsigned short f2bf(float f) {
    unsigned int u = __float_as_uint(f);
    unsigned int r = (u + 0x7FFFu + ((u >> 16) & 1u)) >> 16;   // RNE
    return (unsigned short)r;
}
__device__ __forceinline__ float bf2f(unsigned short h) {
    return __uint_as_float(((unsigned int)h) << 16);
}

// ---------------------------------------------------------------------------
// Stage 1: EvolveGCN-O GRU on the [64,64] weight -> W_new transposed.
// ---------------------------------------------------------------------------
__global__ void evolve_kernel(const float* __restrict__ W,
                              const float* __restrict__ wih,
                              const float* __restrict__ whh,
                              const float* __restrict__ bih,
                              const float* __restrict__ bhh,
                              float* __restrict__ wt) {
    int t = blockIdx.x * blockDim.x + threadIdx.x;
    if (t >= F * F) return;
    int i = t >> 6;
    int j = t & 63;
    const float* Wi = W + i * F;
    float gxr = bih[j], gxz = bih[F + j], gxn = bih[2 * F + j];
    float ghr = bhh[j], ghz = bhh[F + j], ghn = bhh[2 * F + j];
#pragma unroll
    for (int k = 0; k < F; ++k) {
        float wv = Wi[k];
        gxr += wv * wih[(j) * F + k];
        gxz += wv * wih[(F + j) * F + k];
        gxn += wv * wih[(2 * F + j) * F + k];
        ghr += wv * whh[(j) * F + k];
        ghz += wv * whh[(F + j) * F + k];
        ghn += wv * whh[(2 * F + j) * F + k];
    }
    float r = 1.0f / (1.0f + expf(-(gxr + ghr)));
    float z = 1.0f / (1.0f + expf(-(gxz + ghz)));
    float n = tanhf(gxn + r * ghn);
    float wnew = (1.0f - z) * n + z * Wi[j];
    wt[j * F + i] = wnew;                      // transposed: wt[col][k]
}

// ---------------------------------------------------------------------------
// Stage 2: xw16 = bf16( rsqrt(deg[r]) * (x @ W_new) ). dinv[src] folded in.
// ---------------------------------------------------------------------------
__global__ void xw_kernel(const float* __restrict__ x,
                          const float* __restrict__ wt,
                          const float* __restrict__ deg,
                          unsigned short* __restrict__ xw16, int N) {
    int r = blockIdx.x * blockDim.x + threadIdx.x;
    if (r >= N) return;
    float xr[F];
    const nt_float4* xp = (const nt_float4*)(x + (size_t)r * F);
#pragma unroll
    for (int q = 0; q < F / 4; ++q) {
        nt_float4 v = __builtin_nontemporal_load(xp + q);
        xr[4 * q + 0] = v.x; xr[4 * q + 1] = v.y;
        xr[4 * q + 2] = v.z; xr[4 * q + 3] = v.w;
    }
    float dinv = rsqrtf(deg[r]);
    ushort4* op = (ushort4*)(xw16 + (size_t)r * F);
    for (int cb = 0; cb < F / 4; ++cb) {
        const float* w0 = wt + (4 * cb) * F;
        float a0 = 0.f, a1 = 0.f, a2 = 0.f, a3 = 0.f;
#pragma unroll
        for (int k = 0; k < F; ++k) {
            float xv = xr[k];
            a0 += xv * w0[k];
            a1 += xv * w0[F + k];
            a2 += xv * w0[2 * F + k];
            a3 += xv * w0[3 * F + k];
        }
        ushort4 o;
        o.x = f2bf(a0 * dinv); o.y = f2bf(a1 * dinv);
        o.z = f2bf(a2 * dinv); o.w = f2bf(a3 * dinv);
        op[cb] = o;
    }
}

// ---------------------------------------------------------------------------
// Stage 3a: bucket histogram (bucket = dst>>RBSH). LDS int hist per block,
// one global atomic per (block,bucket) at merge.
// ---------------------------------------------------------------------------
__global__ void bhist_kernel(const int* __restrict__ ei, int* __restrict__ ghist,
                             int E, int NB) {
    __shared__ int lh[NBMAX];
    int t = threadIdx.x;
    for (int i = t; i < NB; i += 256) lh[i] = 0;
    __syncthreads();
    int base = blockIdx.x * 4096;
#pragma unroll
    for (int it = 0; it < 16; ++it) {
        int e = base + it * 256 + t;
        if (e < E) atomicAdd(&lh[ei[E + e] >> RBSH], 1);
    }
    __syncthreads();
    for (int i = t; i < NB; i += 256) {
        int c = lh[i];
        if (c) atomicAdd(&ghist[i], c);
    }
}

// ---------------------------------------------------------------------------
// Stage 3b: exclusive scan of NB (<=1024) bucket counts, single 1024-block.
// ---------------------------------------------------------------------------
__global__ void bscan_kernel(const int* __restrict__ ghist, int* __restrict__ boff,
                             int* __restrict__ gcur, int NB) {
    __shared__ int s[1024];
    int t = threadIdx.x;
    int v = (t < NB) ? ghist[t] : 0;
    s[t] = v;
    __syncthreads();
    for (int o = 1; o < 1024; o <<= 1) {
        int u = (t >= o) ? s[t - o] : 0;
        __syncthreads();
        s[t] += u;
        __syncthreads();
    }
    if (t < NB) {
        int excl = s[t] - v;
        boff[t] = excl;
        gcur[t] = excl;
        if (t == NB - 1) boff[NB] = excl + v;   // == E
    }
}

// ---------------------------------------------------------------------------
// Stage 3c (passA): bucketed scatter with per-(block,bucket) contiguous runs
// (one global atomic per (block,bucket); run stores issue back-to-back from
// one CU -> lines fill in local L2, write back once). Proven fast (r8/r9).
// Record: [dl:7 | src:17 | w:15] packed in u64 (dl in bits 32..38).
// ---------------------------------------------------------------------------
__global__ void passA_kernel(const int* __restrict__ ei, const float* __restrict__ ew,
                             int* __restrict__ gcur,
                             unsigned long long* __restrict__ rec, int E, int NB) {
    __shared__ int lh[NBMAX];
    __shared__ int lcur[NBMAX];
    int t = threadIdx.x;
    for (int i = t; i < NB; i += 256) lh[i] = 0;
    __syncthreads();
    int base = blockIdx.x * CHUNKA;
#pragma unroll
    for (int it = 0; it < CHUNKA / 256; ++it) {
        int e = base + it * 256 + t;
        if (e < E) atomicAdd(&lh[ei[E + e] >> RBSH], 1);
    }
    __syncthreads();
    for (int i = t; i < NB; i += 256) {
        int c = lh[i];
        lcur[i] = c ? atomicAdd(&gcur[i], c) : 0;
    }
    __syncthreads();
#pragma unroll
    for (int it = 0; it < CHUNKA / 256; ++it) {
        int e = base + it * 256 + t;
        if (e < E) {
            int dst = ei[E + e];
            int src = ei[e];
            float w = ew[e];
            unsigned int q = (unsigned int)(w * 32767.0f + 0.5f);
            int b = dst >> RBSH;
            int p = atomicAdd(&lcur[b], 1);
            unsigned long long r = ((unsigned long long)(dst & (RB - 1)) << 32)
                                 | ((unsigned long long)((unsigned int)src) << 15) | q;
            rec[p] = r;
        }
    }
}

// ---------------------------------------------------------------------------
// Stage 3d (sortB): block per bucket. Counting-sort the bucket's ~2046
// records by dl with INT LDS counters (native ds ops — the fp32 LDS
// atomicAdd in r8/r9's passB was the 700us disaster). Emits:
//   node_off[node] = CSR offsets (coalesced 128-wide write)
//   rec2[]         = 4B records [src:17|w:15], dst-sorted (8KB window, one CU)
// ---------------------------------------------------------------------------
__global__ void sortB_kernel(const unsigned long long* __restrict__ rec,
                             const int* __restrict__ boff,
                             unsigned int* __restrict__ rec2,
                             int* __restrict__ node_off,
                             int N, int NB) {
    __shared__ int cnt[RB];
    __shared__ int cur[RB];
    int b = blockIdx.x;
    int t = threadIdx.x;            // 256 threads
    int beg = boff[b];
    int end = boff[b + 1];
    if (t < RB) cnt[t] = 0;
    __syncthreads();
    for (int i = beg + t; i < end; i += 256)
        atomicAdd(&cnt[(int)(rec[i] >> 32)], 1);
    __syncthreads();
    if (t < RB) cur[t] = cnt[t];
    __syncthreads();
    for (int o = 1; o < RB; o <<= 1) {            // inclusive scan (128 wide)
        int v = (t < RB && t >= o) ? cur[t - o] : 0;
        __syncthreads();
        if (t < RB) cur[t] += v;
        __syncthreads();
    }
    int node0 = b << RBSH;
    if (t < RB) {
        int excl = cur[t] - cnt[t];
        int node = node0 + t;
        if (node < N) node_off[node] = beg + excl;
        cur[t] = excl;                            // becomes cursor
    }
    if (b == NB - 1 && t == 0) node_off[N] = end; // == E
    __syncthreads();
    for (int i = beg + t; i < end; i += 256) {
        unsigned long long r = rec[i];
        int dl = (int)(r >> 32);
        int p = atomicAdd(&cur[dl], 1);
        rec2[beg + p] = (unsigned int)r;          // [src:17|w:15]
    }
}

// ---------------------------------------------------------------------------
// Stage 4 (segsum): wave per node, REGISTER accumulate (round-7 form, the
// measured-fast consumer). lane = feature. Per edge: 4B broadcast record +
// 128B bf16 row gather. Epilogue: ReLU*lw, shuffle-reduce, *rsqrt(deg), +lb.
// ---------------------------------------------------------------------------
__global__ void segsum_kernel(const unsigned short* __restrict__ xw16,
                              const int* __restrict__ node_off,
                              const unsigned int* __restrict__ rec2,
                              const float* __restrict__ deg,
                              const float* __restrict__ lw,
                              const float* __restrict__ lb,
                              float* __restrict__ out, int M) {
    int gid = blockIdx.x * blockDim.x + threadIdx.x;
    int node = gid >> 6;
    int lane = threadIdx.x & 63;
    if (node >= M) return;
    int beg = node_off[node];
    int end = node_off[node + 1];
    float acc = 0.0f;
    int e = beg;
    const float wscale = 1.0f / 32767.0f;
    for (; e + 3 < end; e += 4) {
        unsigned int r0 = rec2[e];
        unsigned int r1 = rec2[e + 1];
        unsigned int r2 = rec2[e + 2];
        unsigned int r3 = rec2[e + 3];
        float v0 = bf2f(xw16[(size_t)(r0 >> 15) * F + lane]);
        float v1 = bf2f(xw16[(size_t)(r1 >> 15) * F + lane]);
        float v2 = bf2f(xw16[(size_t)(r2 >> 15) * F + lane]);
        float v3 = bf2f(xw16[(size_t)(r3 >> 15) * F + lane]);
        acc += (float)(r0 & 32767u) * wscale * v0;
        acc += (float)(r1 & 32767u) * wscale * v1;
        acc += (float)(r2 & 32767u) * wscale * v2;
        acc += (float)(r3 & 32767u) * wscale * v3;
    }
    for (; e < end; ++e) {
        unsigned int r = rec2[e];
        acc += (float)(r & 32767u) * wscale * bf2f(xw16[(size_t)(r >> 15) * F + lane]);
    }
    acc = fmaxf(acc, 0.0f) * lw[lane];
#pragma unroll
    for (int o = 32; o; o >>= 1) acc += __shfl_xor(acc, o, 64);
    if (lane == 0) out[node] = acc * rsqrtf(deg[node]) + lb[0];
}

extern "C" void kernel_launch(void* const* d_in, const int* in_sizes, int n_in,
                              void* d_out, int out_size, void* d_ws, size_t ws_size,
                              hipStream_t stream) {
    const float* x   = (const float*)d_in[0];
    const int*   ei  = (const int*)d_in[1];
    const float* ew  = (const float*)d_in[2];
    const float* deg = (const float*)d_in[3];
    const float* W0  = (const float*)d_in[5];
    const float* wih = (const float*)d_in[6];
    const float* whh = (const float*)d_in[7];
    const float* bih = (const float*)d_in[8];
    const float* bhh = (const float*)d_in[9];
    const float* lw  = (const float*)d_in[10];
    const float* lb  = (const float*)d_in[11];
    float* out = (float*)d_out;

    int N = in_sizes[0] / F;        // 100000
    int E = in_sizes[1] / 2;        // 1600000
    int M = out_size;               // target_num
    int NB = (N + RB - 1) / RB;     // 782 (<= NBMAX, <= 1024)

    // workspace layout (8B alignment maintained for rec)
    float*              wt       = (float*)d_ws;                      // 8192 f (32KB)
    unsigned short*     xw16     = (unsigned short*)(wt + 8192);      // N*F bf16 (12.8MB)
    unsigned long long* rec      = (unsigned long long*)(xw16 + (size_t)N * F); // E u64
    unsigned int*       rec2     = (unsigned int*)(rec + E);          // E u32 (6.4MB)
    int*                node_off = (int*)(rec2 + E);                  // N+1
    int*                ghist    = node_off + N + 8;                  // NB
    int*                boff     = ghist + NBMAX;                     // NB+1
    int*                gcur     = boff + NBMAX + 8;                  // NB

    evolve_kernel<<<(F * F + 255) / 256, 256, 0, stream>>>(W0, wih, whh, bih, bhh, wt);

    (void)hipMemsetAsync(ghist, 0, (size_t)NBMAX * sizeof(int), stream);

    xw_kernel<<<(N + 255) / 256, 256, 0, stream>>>(x, wt, deg, xw16, N);

    bhist_kernel<<<(E + 4095) / 4096, 256, 0, stream>>>(ei, ghist, E, NB);

    bscan_kernel<<<1, 1024, 0, stream>>>(ghist, boff, gcur, NB);

    passA_kernel<<<(E + CHUNKA - 1) / CHUNKA, 256, 0, stream>>>(ei, ew, gcur, rec, E, NB);

    sortB_kernel<<<NB, 256, 0, stream>>>(rec, boff, rec2, node_off, N, NB);

    {
        long long threads = (long long)M * 64;
        int blocks = (int)((threads + 255) / 256);
        segsum_kernel<<<blocks, 256, 0, stream>>>(xw16, node_off, rec2, deg, lw, lb, out, M);
    }
}